// Round 10
// baseline (84.606 us; speedup 1.0000x reference)
//
#include <hip/hip_runtime.h>

typedef unsigned long long u64;
typedef _Float16 f16x8 __attribute__((ext_vector_type(8)));
typedef float    f32x4 __attribute__((ext_vector_type(4)));
typedef __fp16   fp16x2 __attribute__((ext_vector_type(2)));

#define G_    4096
#define NPTS  16384

union H8 { _Float16 h[8]; uint4 u; };
union PK2 { fp16x2 h[2]; uint2 u; };
union PK4 { fp16x2 h[4]; uint4 u; };

#define MFMA_(A_,B_,C_) __builtin_amdgcn_mfma_f32_16x16x32_f16((A_),(B_),(C_),0,0,0)

// ---------------- ws layout (bytes) ----------------
// pc   i32 [16][16384]    @ 0        (1048576)
// w1f  f16 [16][3][64][8] @ 1048576  (49152)   A-frag order, 3 k-tiles (k=64..95 pad/noise)
// w2f  f16 [16][8][64][8] @ 1097728  (131072)
// w3f  f16 [8][64][8]     @ 1228800  (8192)    rows 3..15 zero
// xT   f16 [16][4096][64] @ 1236992  (8388608) transposed+f16 x (only if ws fits)
// total 9625600

#define OFF_W1F 1048576
#define OFF_W2F 1097728
#define OFF_W3F 1228800
#define OFF_XT  1236992
#define WS_NEED (OFF_XT + 8388608)

// ---- merged prep ----
// blocks 0..15   : sampling (one per batch)
// blocks 16..61  : weight bake (11776 H8 entries)
// blocks 62..317 : x transpose -> f16 (only launched when use_xt)
__global__ __launch_bounds__(256) void kP(const float* __restrict__ dens,
                                          int* __restrict__ pc,
                                          const float* __restrict__ W1,
                                          const float* __restrict__ W2,
                                          const float* __restrict__ W3,
                                          const float* __restrict__ x,
                                          _Float16* __restrict__ w1f,
                                          _Float16* __restrict__ w2f,
                                          _Float16* __restrict__ w3f,
                                          _Float16* __restrict__ xT){
  __shared__ double sred[256];
  __shared__ u64  keys[4096];     // 32 KB
  __shared__ int  nvs[4096];      // 16 KB
  __shared__ int  binidx[4096];   // 16 KB
  __shared__ int  hist[1024];
  __shared__ int  cab[1024];
  __shared__ int  scan[256];
  __shared__ float Sf;
  __shared__ int  remS, BstarS, needS, cntS;
  const int t = threadIdx.x;

  if (blockIdx.x >= 62){
    // ---------------- x transpose path: [64][4096] f32 -> [4096][64] f16 ----------------
    const int idx = blockIdx.x - 62;          // 0..255
    const int b = idx >> 4, blk = idx & 15;
    const int cell = blk*256 + t;
    const float* xb = x + ((size_t)b*64)*G_ + cell;
    _Float16* xo = xT + ((size_t)(b*G_ + cell))*64;
    #pragma unroll
    for (int c8 = 0; c8 < 8; ++c8){
      float a[8];
      #pragma unroll
      for (int j = 0; j < 8; ++j) a[j] = xb[(size_t)(c8*8 + j)*G_];
      PK4 v;
      v.h[0] = __builtin_amdgcn_cvt_pkrtz(a[0], a[1]);
      v.h[1] = __builtin_amdgcn_cvt_pkrtz(a[2], a[3]);
      v.h[2] = __builtin_amdgcn_cvt_pkrtz(a[4], a[5]);
      v.h[3] = __builtin_amdgcn_cvt_pkrtz(a[6], a[7]);
      *(uint4*)&xo[c8*8] = v.u;
    }
    return;
  }

  if (blockIdx.x >= 16){
    // ---------------- weight bake path ----------------
    const int e = (blockIdx.x - 16)*256 + t;   // 11776 entries
    H8 v;
    if (e < 8192){                                 // w2f: [RT 16][kt 8][lane 64]
      const int RT = e >> 9, kt = (e >> 6) & 7, l = e & 63;
      const int m = RT*16 + (l & 15), k = kt*32 + ((l >> 4) << 3);
      #pragma unroll
      for (int j = 0; j < 8; ++j) v.h[j] = (_Float16)W2[m*256 + k + j];
      *(uint4*)&w2f[e*8] = v.u;
    } else if (e < 11264){                         // w1f: [RT 16][kt 3][lane 64]
      const int e2 = e - 8192;
      const int RT = e2 / 192, r2 = e2 % 192, kt = r2 >> 6, l = r2 & 63;
      const int m = RT*16 + (l & 15), k = kt*32 + ((l >> 4) << 3);
      #pragma unroll
      for (int j = 0; j < 8; ++j) v.h[j] = (k + j < 66) ? (_Float16)W1[m*66 + k + j] : (_Float16)0.f;
      *(uint4*)&w1f[e2*8] = v.u;
    } else if (e < 11776){                         // w3f: [kt 8][lane 64]
      const int e3 = e - 11264;
      const int kt = e3 >> 6, l = e3 & 63;
      const int m = l & 15, k = kt*32 + ((l >> 4) << 3);
      #pragma unroll
      for (int j = 0; j < 8; ++j) v.h[j] = (m < 3) ? (_Float16)W3[m*256 + k + j] : (_Float16)0.f;
      *(uint4*)&w3f[e3*8] = v.u;
    }
    return;
  }

  // ---------------- sampling path (one block per batch) ----------------
  const int b = blockIdx.x;
  const float* d = dens + b*G_;

  for (int j = t; j < 1024; j += 256) hist[j] = 0;
  if (t == 0) cntS = 0;

  // exact same summation pattern as passing rounds: per-thread d[t+256j], tree over 256
  double s = 0.0;
  for (int j = 0; j < 16; ++j) s += (double)d[t + 256*j];
  sred[t] = s; __syncthreads();
  for (int off = 128; off > 0; off >>= 1){
    if (t < off) sred[t] += sred[t + off];
    __syncthreads();
  }
  if (t == 0) Sf = (float)sred[0];
  __syncthreads();
  const float S = Sf;

  int bi[16]; int bs = 0;
  #pragma unroll
  for (int j = 0; j < 16; ++j){
    const int i = t + 256*j;
    const float p  = d[i] / S;
    const float sc = p * 16384.0f;     // exact (x2^14)
    const float fl = floorf(sc);
    const float fr = sc - fl;          // exact
    bi[j] = (int)fl; bs += bi[j];
    const unsigned fb = __float_as_uint(fr);
    keys[i] = ((u64)fb << 12) | (u64)(4095 - i);
    atomicAdd(&hist[fb >> 20], 1);
  }
  scan[t] = bs; __syncthreads();
  for (int off = 128; off > 0; off >>= 1){
    if (t < off) scan[t] += scan[t + off];
    __syncthreads();
  }
  if (t == 0) remS = 16384 - scan[0];
  __syncthreads();
  const int rem = remS;

  // suffix-scan histogram (1024 bins, 4/thread) -> cab[q] = #keys in bins > q
  const int h0 = hist[4*t], h1 = hist[4*t+1], h2 = hist[4*t+2], h3 = hist[4*t+3];
  const int gs = h0 + h1 + h2 + h3;
  __syncthreads();
  scan[t] = gs; __syncthreads();
  for (int off = 1; off < 256; off <<= 1){
    const int v2 = (t + off < 256) ? scan[t + off] : 0;
    __syncthreads();
    scan[t] += v2;
    __syncthreads();
  }
  const int sAfter = scan[t] - gs;
  cab[4*t+3] = sAfter;
  cab[4*t+2] = sAfter + h3;
  cab[4*t+1] = sAfter + h3 + h2;
  cab[4*t+0] = sAfter + h3 + h2 + h1;
  if (t == 0){ BstarS = 0x7fffffff; needS = 0; }
  __syncthreads();
  if (rem > 0){
    const int ca[4] = {cab[4*t], cab[4*t+1], cab[4*t+2], cab[4*t+3]};
    const int hh[4] = {h0, h1, h2, h3};
    #pragma unroll
    for (int q = 0; q < 4; ++q)
      if (ca[q] < rem && rem <= ca[q] + hh[q]){ BstarS = 4*t + q; needS = rem - ca[q]; }
  }
  __syncthreads();
  const int Bstar = BstarS, need = needS;

  #pragma unroll
  for (int j = 0; j < 16; ++j){
    const int i = t + 256*j;
    const int bin = (int)(keys[i] >> 32);
    nvs[i] = bi[j] + ((bin > Bstar) ? 1 : 0);
    if (bin == Bstar){ const int pos = atomicAdd(&cntS, 1); binidx[pos] = i; }
  }
  __syncthreads();
  const int cnt = cntS;
  for (int p = t; p < cnt; p += 256){
    const u64 K = keys[binidx[p]];
    int r = 0;
    for (int q = 0; q < cnt; ++q) r += (keys[binidx[q]] > K) ? 1 : 0;
    if (r < need) nvs[binidx[p]] += 1;
  }
  __syncthreads();

  // prefix + expand (thread t owns cells t*16..t*16+15)
  int loc[16]; int ls = 0;
  #pragma unroll
  for (int j = 0; j < 16; ++j){ loc[j] = nvs[t*16 + j]; ls += loc[j]; }
  __syncthreads();
  scan[t] = ls; __syncthreads();
  for (int off = 1; off < 256; off <<= 1){
    const int v2 = (t >= off) ? scan[t - off] : 0;
    __syncthreads();
    scan[t] += v2;
    __syncthreads();
  }
  int off0 = scan[t] - ls;
  int* o = pc + b*NPTS;
  #pragma unroll
  for (int j = 0; j < 16; ++j){
    const int c = t*16 + j;
    for (int r = 0; r < loc[j]; ++r) o[off0++] = c;
  }
}

// ---- fused MLP via f16 MFMA: 64 pts/block, 8 waves x 32 rows -> 32 acc regs/thread ----
// regs ~105 < 128 => __launch_bounds__(512,4): 4 waves/SIMD, 2 blocks/CU, 16 waves/CU.
template<bool USE_XT>
__global__ __launch_bounds__(512, 4) void kE(
    const float* __restrict__ x, const _Float16* __restrict__ xT,
    const float* __restrict__ noise,
    const _Float16* __restrict__ w1f, const _Float16* __restrict__ w2f,
    const _Float16* __restrict__ w3f,
    const float* __restrict__ b1, const float* __restrict__ b2, const float* __restrict__ b3,
    const int* __restrict__ pc, float* __restrict__ out)
{
  __shared__ _Float16 Hb[16384];   // 32KB; reused: Bin(12KB) -> Bh1(32KB) -> Bh2(32KB)
  __shared__ int cells[64];
  const int b = blockIdx.y, p0 = blockIdx.x*64, tid = threadIdx.x;
  const int w = tid >> 6, lane = tid & 63;

  if (tid < 64) cells[tid] = pc[b*NPTS + p0 + tid];

  // ---- stage noise k-tile (kt=2): rows k=64,65 = noise, rest zero (threads 0..255) ----
  if (tid < 256){
    const int ct = tid >> 6, l2 = tid & 63;
    const int k2 = l2 >> 4, pt = ct*16 + (l2 & 15);
    PK4 v; v.u = make_uint4(0u, 0u, 0u, 0u);
    if (k2 == 0){
      const float n0 = noise[(b*2 + 0)*NPTS + p0 + pt]*2.f - 1.f;
      const float n1 = noise[(b*2 + 1)*NPTS + p0 + pt]*2.f - 1.f;
      v.h[0] = __builtin_amdgcn_cvt_pkrtz(n0, n1);
    }
    *(uint4*)&Hb[((2*4 + ct)*64 + l2)*8] = v.u;
  }

  // ---- stage layer-1 x k-tiles (kt=0,1): single pass, 512 tasks ----
  // thread -> (pt = tid&63, koct = tid>>6): 64 consecutive threads write
  // lane-linear 16B-strided LDS addresses -> conflict-free.
  {
    const int pt = tid & 63;
    const int cell = pc[b*NPTS + p0 + pt];
    const int ct = pt >> 4, sl = pt & 15;
    const int koct = tid >> 6;
    const int kt = koct >> 2, k2 = koct & 3;
    const int lane2 = sl + k2*16;
    if (USE_XT){
      const uint4 v = *(const uint4*)&xT[((size_t)(b*G_ + cell))*64 + koct*8];
      *(uint4*)&Hb[((kt*4 + ct)*64 + lane2)*8] = v;
    } else {
      const float* xb = x + ((size_t)(b*64 + koct*8))*G_ + cell;
      float a[8];
      #pragma unroll
      for (int j = 0; j < 8; ++j) a[j] = xb[(size_t)j*G_];
      PK4 v;
      v.h[0] = __builtin_amdgcn_cvt_pkrtz(a[0], a[1]);
      v.h[1] = __builtin_amdgcn_cvt_pkrtz(a[2], a[3]);
      v.h[2] = __builtin_amdgcn_cvt_pkrtz(a[4], a[5]);
      v.h[3] = __builtin_amdgcn_cvt_pkrtz(a[6], a[7]);
      *(uint4*)&Hb[((kt*4 + ct)*64 + lane2)*8] = v.u;
    }
  }
  __syncthreads();

  f32x4 acc[2][4];
  const f32x4 zz = {0.f, 0.f, 0.f, 0.f};
  #pragma unroll
  for (int rt = 0; rt < 2; ++rt)
    #pragma unroll
    for (int ct = 0; ct < 4; ++ct) acc[rt][ct] = zz;

  const int wr = w*2;   // row-tile base (2 tiles of 16 rows per wave)

  // -------- layer 1: K=96 (3 k-tiles; tile 2 = noise rows) --------
  __builtin_amdgcn_s_setprio(1);
  #pragma unroll
  for (int kt = 0; kt < 3; ++kt){
    f16x8 B[4];
    #pragma unroll
    for (int ct = 0; ct < 4; ++ct) B[ct] = *(f16x8*)&Hb[((kt*4 + ct)*64 + lane)*8];
    #pragma unroll
    for (int rt = 0; rt < 2; ++rt){
      f16x8 A = *(const f16x8*)&w1f[(((wr + rt)*3 + kt)*64 + lane)*8];
      #pragma unroll
      for (int ct = 0; ct < 4; ++ct)
        acc[rt][ct] = MFMA_(A, B[ct], acc[rt][ct]);
    }
  }
  __builtin_amdgcn_s_setprio(0);
  __syncthreads();

  // -------- epilogue L1: bias+relu -> f16 fragment order (Bh1), pkrtz --------
  #pragma unroll
  for (int rt = 0; rt < 2; ++rt){
    const int row0 = w*32 + rt*16 + ((lane >> 4) << 2);
    const float4 bq = *(const float4*)&b1[row0];
    const int kt2 = row0 >> 5, c16 = (row0 >> 3) & 3, j0 = row0 & 7;
    const int lane2 = (lane & 15) + c16*16;
    #pragma unroll
    for (int ct = 0; ct < 4; ++ct){
      PK2 v;
      v.h[0] = __builtin_amdgcn_cvt_pkrtz(fmaxf(acc[rt][ct][0] + bq.x, 0.f),
                                          fmaxf(acc[rt][ct][1] + bq.y, 0.f));
      v.h[1] = __builtin_amdgcn_cvt_pkrtz(fmaxf(acc[rt][ct][2] + bq.z, 0.f),
                                          fmaxf(acc[rt][ct][3] + bq.w, 0.f));
      *(uint2*)&Hb[((kt2*4 + ct)*64 + lane2)*8 + j0] = v.u;
      acc[rt][ct] = zz;
    }
  }
  __syncthreads();

  // -------- layer 2: K=256 (8 k-tiles), simple loop (compiler schedules) --------
  __builtin_amdgcn_s_setprio(1);
  #pragma unroll 4
  for (int kt = 0; kt < 8; ++kt){
    f16x8 B[4];
    #pragma unroll
    for (int ct = 0; ct < 4; ++ct) B[ct] = *(f16x8*)&Hb[((kt*4 + ct)*64 + lane)*8];
    #pragma unroll
    for (int rt = 0; rt < 2; ++rt){
      f16x8 A = *(const f16x8*)&w2f[(((wr + rt)*8 + kt)*64 + lane)*8];
      #pragma unroll
      for (int ct = 0; ct < 4; ++ct)
        acc[rt][ct] = MFMA_(A, B[ct], acc[rt][ct]);
    }
  }
  __builtin_amdgcn_s_setprio(0);

  // ---- preload layer-3 A-frags (waves 0..3 only; hide under epilogue L2) ----
  f16x8 W3v[8];
  if (w < 4){
    #pragma unroll
    for (int kt = 0; kt < 8; ++kt) W3v[kt] = *(const f16x8*)&w3f[(kt*64 + lane)*8];
  }
  __syncthreads();

  // -------- epilogue L2: bias+relu -> f16 fragment order (Bh2), pkrtz --------
  #pragma unroll
  for (int rt = 0; rt < 2; ++rt){
    const int row0 = w*32 + rt*16 + ((lane >> 4) << 2);
    const float4 bq = *(const float4*)&b2[row0];
    const int kt2 = row0 >> 5, c16 = (row0 >> 3) & 3, j0 = row0 & 7;
    const int lane2 = (lane & 15) + c16*16;
    #pragma unroll
    for (int ct = 0; ct < 4; ++ct){
      PK2 v;
      v.h[0] = __builtin_amdgcn_cvt_pkrtz(fmaxf(acc[rt][ct][0] + bq.x, 0.f),
                                          fmaxf(acc[rt][ct][1] + bq.y, 0.f));
      v.h[1] = __builtin_amdgcn_cvt_pkrtz(fmaxf(acc[rt][ct][2] + bq.z, 0.f),
                                          fmaxf(acc[rt][ct][3] + bq.w, 0.f));
      *(uint2*)&Hb[((kt2*4 + ct)*64 + lane2)*8 + j0] = v.u;
    }
  }
  __syncthreads();

  // -------- layer 3: rows 0..2, waves 0..3 handle col-tile w --------
  if (w < 4){
    f32x4 a3 = zz;
    __builtin_amdgcn_s_setprio(1);
    #pragma unroll
    for (int kt = 0; kt < 8; ++kt){
      f16x8 B = *(f16x8*)&Hb[((kt*4 + w)*64 + lane)*8];
      a3 = MFMA_(W3v[kt], B, a3);
    }
    __builtin_amdgcn_s_setprio(0);
    if (lane < 16){
      const float ox = a3[0] + b3[0];
      const float oy = a3[1] + b3[1];
      const float oz = a3[2] + b3[2];
      const float nrm = sqrtf(ox*ox + oy*oy + oz*oz);
      const float rg_ = fmaxf(nrm - (float)0.10825317547305482, 0.f);
      const int pt = w*16 + lane;
      const int cell = cells[pt];
      const float fx = ((float)(cell >> 8)        + 0.5f) * 0.0625f - 0.5f;
      const float fy = ((float)((cell >> 4) & 15) + 0.5f) * 0.0625f - 0.5f;
      const float fz = ((float)(cell & 15)        + 0.5f) * 0.0625f - 0.5f;
      const int pidx = p0 + pt;
      out[b*49152 +          pidx] = ox + fx;
      out[b*49152 + 16384 +  pidx] = oy + fy;
      out[b*49152 + 32768 +  pidx] = oz + fz;
      out[786432  + b*16384 + pidx] = rg_;
    }
  }
}

extern "C" void kernel_launch(void* const* d_in, const int* in_sizes, int n_in,
                              void* d_out, int out_size, void* d_ws, size_t ws_size,
                              hipStream_t stream){
  const float* x     = (const float*)d_in[0];
  const float* dens  = (const float*)d_in[1];
  const float* noise = (const float*)d_in[2];
  const float* W1    = (const float*)d_in[3];
  const float* b1    = (const float*)d_in[4];
  const float* W2    = (const float*)d_in[5];
  const float* b2    = (const float*)d_in[6];
  const float* W3    = (const float*)d_in[7];
  const float* b3    = (const float*)d_in[8];

  char* ws = (char*)d_ws;
  int*      pc   = (int*)(ws + 0);
  _Float16* w1f  = (_Float16*)(ws + OFF_W1F);
  _Float16* w2f  = (_Float16*)(ws + OFF_W2F);
  _Float16* w3f  = (_Float16*)(ws + OFF_W3F);
  _Float16* xT   = (_Float16*)(ws + OFF_XT);
  float*    out  = (float*)d_out;

  const bool use_xt = (ws_size >= (size_t)WS_NEED);
  const int  nprep  = use_xt ? 318 : 62;

  kP<<<dim3(nprep), dim3(256), 0, stream>>>(dens, pc, W1, W2, W3, x,
                                            w1f, w2f, w3f, xT);
  if (use_xt)
    kE<true ><<<dim3(256, 16), dim3(512), 0, stream>>>(x, xT, noise, w1f, w2f, w3f,
                                                       b1, b2, b3, pc, out);
  else
    kE<false><<<dim3(256, 16), dim3(512), 0, stream>>>(x, xT, noise, w1f, w2f, w3f,
                                                       b1, b2, b3, pc, out);
}

// Round 11
// 76.109 us; speedup vs baseline: 1.1116x; 1.1116x over previous
//
#include <hip/hip_runtime.h>

typedef unsigned long long u64;
typedef _Float16 f16x8 __attribute__((ext_vector_type(8)));
typedef float    f32x4 __attribute__((ext_vector_type(4)));
typedef __fp16   fp16x2 __attribute__((ext_vector_type(2)));

#define G_    4096
#define NPTS  16384

union H8 { _Float16 h[8]; uint4 u; };
union PK2 { fp16x2 h[2]; uint2 u; };
union PK4 { fp16x2 h[4]; uint4 u; };

#define MFMA_(A_,B_,C_) __builtin_amdgcn_mfma_f32_16x16x32_f16((A_),(B_),(C_),0,0,0)

// ---------------- ws layout (bytes) ----------------
// pc   i32 [16][16384]    @ 0        (1048576)
// w1f  f16 [16][3][64][8] @ 1048576  (49152)   A-frag order, 3 k-tiles (k=64..95 pad/noise)
// w2f  f16 [16][8][64][8] @ 1097728  (131072)
// w3f  f16 [8][64][8]     @ 1228800  (8192)    rows 3..15 zero
// xT   f16 [16][4096][64] @ 1236992  (8388608) transposed+f16 x (only if ws fits)
// total 9625600

#define OFF_W1F 1048576
#define OFF_W2F 1097728
#define OFF_W3F 1228800
#define OFF_XT  1236992
#define WS_NEED (OFF_XT + 8388608)

// ---- merged prep ----
// blocks 0..15   : sampling (one per batch)
// blocks 16..61  : weight bake (11776 H8 entries)
// blocks 62..317 : x transpose -> f16 (only launched when use_xt)
__global__ __launch_bounds__(256) void kP(const float* __restrict__ dens,
                                          int* __restrict__ pc,
                                          const float* __restrict__ W1,
                                          const float* __restrict__ W2,
                                          const float* __restrict__ W3,
                                          const float* __restrict__ x,
                                          _Float16* __restrict__ w1f,
                                          _Float16* __restrict__ w2f,
                                          _Float16* __restrict__ w3f,
                                          _Float16* __restrict__ xT){
  __shared__ double sred[256];
  __shared__ u64  keys[4096];     // 32 KB
  __shared__ int  nvs[4096];      // 16 KB
  __shared__ int  binidx[4096];   // 16 KB
  __shared__ int  hist[1024];
  __shared__ int  cab[1024];
  __shared__ int  scan[256];
  __shared__ float Sf;
  __shared__ int  remS, BstarS, needS, cntS;
  const int t = threadIdx.x;

  if (blockIdx.x >= 62){
    // ---------------- x transpose path: [64][4096] f32 -> [4096][64] f16 ----------------
    const int idx = blockIdx.x - 62;          // 0..255
    const int b = idx >> 4, blk = idx & 15;
    const int cell = blk*256 + t;
    const float* xb = x + ((size_t)b*64)*G_ + cell;
    _Float16* xo = xT + ((size_t)(b*G_ + cell))*64;
    #pragma unroll
    for (int c8 = 0; c8 < 8; ++c8){
      float a[8];
      #pragma unroll
      for (int j = 0; j < 8; ++j) a[j] = xb[(size_t)(c8*8 + j)*G_];
      PK4 v;
      v.h[0] = __builtin_amdgcn_cvt_pkrtz(a[0], a[1]);
      v.h[1] = __builtin_amdgcn_cvt_pkrtz(a[2], a[3]);
      v.h[2] = __builtin_amdgcn_cvt_pkrtz(a[4], a[5]);
      v.h[3] = __builtin_amdgcn_cvt_pkrtz(a[6], a[7]);
      *(uint4*)&xo[c8*8] = v.u;
    }
    return;
  }

  if (blockIdx.x >= 16){
    // ---------------- weight bake path ----------------
    const int e = (blockIdx.x - 16)*256 + t;   // 11776 entries
    H8 v;
    if (e < 8192){                                 // w2f: [RT 16][kt 8][lane 64]
      const int RT = e >> 9, kt = (e >> 6) & 7, l = e & 63;
      const int m = RT*16 + (l & 15), k = kt*32 + ((l >> 4) << 3);
      #pragma unroll
      for (int j = 0; j < 8; ++j) v.h[j] = (_Float16)W2[m*256 + k + j];
      *(uint4*)&w2f[e*8] = v.u;
    } else if (e < 11264){                         // w1f: [RT 16][kt 3][lane 64]
      const int e2 = e - 8192;
      const int RT = e2 / 192, r2 = e2 % 192, kt = r2 >> 6, l = r2 & 63;
      const int m = RT*16 + (l & 15), k = kt*32 + ((l >> 4) << 3);
      #pragma unroll
      for (int j = 0; j < 8; ++j) v.h[j] = (k + j < 66) ? (_Float16)W1[m*66 + k + j] : (_Float16)0.f;
      *(uint4*)&w1f[e2*8] = v.u;
    } else if (e < 11776){                         // w3f: [kt 8][lane 64]
      const int e3 = e - 11264;
      const int kt = e3 >> 6, l = e3 & 63;
      const int m = l & 15, k = kt*32 + ((l >> 4) << 3);
      #pragma unroll
      for (int j = 0; j < 8; ++j) v.h[j] = (m < 3) ? (_Float16)W3[m*256 + k + j] : (_Float16)0.f;
      *(uint4*)&w3f[e3*8] = v.u;
    }
    return;
  }

  // ---------------- sampling path (one block per batch) ----------------
  const int b = blockIdx.x;
  const float* d = dens + b*G_;

  for (int j = t; j < 1024; j += 256) hist[j] = 0;
  if (t == 0) cntS = 0;

  // exact same summation pattern as passing rounds: per-thread d[t+256j], tree over 256
  double s = 0.0;
  for (int j = 0; j < 16; ++j) s += (double)d[t + 256*j];
  sred[t] = s; __syncthreads();
  for (int off = 128; off > 0; off >>= 1){
    if (t < off) sred[t] += sred[t + off];
    __syncthreads();
  }
  if (t == 0) Sf = (float)sred[0];
  __syncthreads();
  const float S = Sf;

  int bi[16]; int bs = 0;
  #pragma unroll
  for (int j = 0; j < 16; ++j){
    const int i = t + 256*j;
    const float p  = d[i] / S;
    const float sc = p * 16384.0f;     // exact (x2^14)
    const float fl = floorf(sc);
    const float fr = sc - fl;          // exact
    bi[j] = (int)fl; bs += bi[j];
    const unsigned fb = __float_as_uint(fr);
    keys[i] = ((u64)fb << 12) | (u64)(4095 - i);
    atomicAdd(&hist[fb >> 20], 1);
  }
  scan[t] = bs; __syncthreads();
  for (int off = 128; off > 0; off >>= 1){
    if (t < off) scan[t] += scan[t + off];
    __syncthreads();
  }
  if (t == 0) remS = 16384 - scan[0];
  __syncthreads();
  const int rem = remS;

  // suffix-scan histogram (1024 bins, 4/thread) -> cab[q] = #keys in bins > q
  const int h0 = hist[4*t], h1 = hist[4*t+1], h2 = hist[4*t+2], h3 = hist[4*t+3];
  const int gs = h0 + h1 + h2 + h3;
  __syncthreads();
  scan[t] = gs; __syncthreads();
  for (int off = 1; off < 256; off <<= 1){
    const int v2 = (t + off < 256) ? scan[t + off] : 0;
    __syncthreads();
    scan[t] += v2;
    __syncthreads();
  }
  const int sAfter = scan[t] - gs;
  cab[4*t+3] = sAfter;
  cab[4*t+2] = sAfter + h3;
  cab[4*t+1] = sAfter + h3 + h2;
  cab[4*t+0] = sAfter + h3 + h2 + h1;
  if (t == 0){ BstarS = 0x7fffffff; needS = 0; }
  __syncthreads();
  if (rem > 0){
    const int ca[4] = {cab[4*t], cab[4*t+1], cab[4*t+2], cab[4*t+3]};
    const int hh[4] = {h0, h1, h2, h3};
    #pragma unroll
    for (int q = 0; q < 4; ++q)
      if (ca[q] < rem && rem <= ca[q] + hh[q]){ BstarS = 4*t + q; needS = rem - ca[q]; }
  }
  __syncthreads();
  const int Bstar = BstarS, need = needS;

  #pragma unroll
  for (int j = 0; j < 16; ++j){
    const int i = t + 256*j;
    const int bin = (int)(keys[i] >> 32);
    nvs[i] = bi[j] + ((bin > Bstar) ? 1 : 0);
    if (bin == Bstar){ const int pos = atomicAdd(&cntS, 1); binidx[pos] = i; }
  }
  __syncthreads();
  const int cnt = cntS;
  for (int p = t; p < cnt; p += 256){
    const u64 K = keys[binidx[p]];
    int r = 0;
    for (int q = 0; q < cnt; ++q) r += (keys[binidx[q]] > K) ? 1 : 0;
    if (r < need) nvs[binidx[p]] += 1;
  }
  __syncthreads();

  // prefix + expand (thread t owns cells t*16..t*16+15)
  int loc[16]; int ls = 0;
  #pragma unroll
  for (int j = 0; j < 16; ++j){ loc[j] = nvs[t*16 + j]; ls += loc[j]; }
  __syncthreads();
  scan[t] = ls; __syncthreads();
  for (int off = 1; off < 256; off <<= 1){
    const int v2 = (t >= off) ? scan[t - off] : 0;
    __syncthreads();
    scan[t] += v2;
    __syncthreads();
  }
  int off0 = scan[t] - ls;
  int* o = pc + b*NPTS;
  #pragma unroll
  for (int j = 0; j < 16; ++j){
    const int c = t*16 + j;
    for (int r = 0; r < loc[j]; ++r) o[off0++] = c;
  }
}

// ---- fused MLP: 128 pts/block, 8 waves x 32 rows x 128 pts, acc = 64 regs ----
// regs ~110 < 128 => (512,4): 4 waves/SIMD, 2 blocks/CU (LDS 64.8KB), 16 waves/CU.
template<bool USE_XT>
__global__ __launch_bounds__(512, 4) void kE(
    const float* __restrict__ x, const _Float16* __restrict__ xT,
    const float* __restrict__ noise,
    const _Float16* __restrict__ w1f, const _Float16* __restrict__ w2f,
    const _Float16* __restrict__ w3f,
    const float* __restrict__ b1, const float* __restrict__ b2, const float* __restrict__ b3,
    const int* __restrict__ pc, float* __restrict__ out)
{
  __shared__ _Float16 Hb[32768];   // 64KB; reused: Bin(24KB) -> Bh1(64KB) -> Bh2(64KB)
  __shared__ int cells[128];
  const int b = blockIdx.y, p0 = blockIdx.x*128, tid = threadIdx.x;
  const int w = tid >> 6, lane = tid & 63;

  if (tid < 128) cells[tid] = pc[b*NPTS + p0 + tid];

  // ---- stage noise k-tile (kt=2): rows k=64,65 = noise, rest zero ----
  {
    const int ct = tid >> 6, l2 = tid & 63;            // ct 0..7
    const int k2 = l2 >> 4, pt = ct*16 + (l2 & 15);
    PK4 v; v.u = make_uint4(0u, 0u, 0u, 0u);
    if (k2 == 0){
      const float n0 = noise[(b*2 + 0)*NPTS + p0 + pt]*2.f - 1.f;
      const float n1 = noise[(b*2 + 1)*NPTS + p0 + pt]*2.f - 1.f;
      v.h[0] = __builtin_amdgcn_cvt_pkrtz(n0, n1);
    }
    *(uint4*)&Hb[((2*8 + ct)*64 + l2)*8] = v.u;
  }

  // ---- stage layer-1 x k-tiles (kt=0,1): 1024 tasks, 2 per thread ----
  // thread -> (pt = tid&127, koct = tid>>7 + 4i): lane-linear 16B-strided writes.
  {
    const int pt = tid & 127;
    const int cell = pc[b*NPTS + p0 + pt];
    const int ct = pt >> 4, sl = pt & 15;
    #pragma unroll
    for (int i = 0; i < 2; ++i){
      const int koct = (tid >> 7) + 4*i;
      const int kt = koct >> 2, k2 = koct & 3;
      const int lane2 = sl + k2*16;
      if (USE_XT){
        const uint4 v = *(const uint4*)&xT[((size_t)(b*G_ + cell))*64 + koct*8];
        *(uint4*)&Hb[((kt*8 + ct)*64 + lane2)*8] = v;
      } else {
        const float* xb = x + ((size_t)(b*64 + koct*8))*G_ + cell;
        float a[8];
        #pragma unroll
        for (int j = 0; j < 8; ++j) a[j] = xb[(size_t)j*G_];
        PK4 v;
        v.h[0] = __builtin_amdgcn_cvt_pkrtz(a[0], a[1]);
        v.h[1] = __builtin_amdgcn_cvt_pkrtz(a[2], a[3]);
        v.h[2] = __builtin_amdgcn_cvt_pkrtz(a[4], a[5]);
        v.h[3] = __builtin_amdgcn_cvt_pkrtz(a[6], a[7]);
        *(uint4*)&Hb[((kt*8 + ct)*64 + lane2)*8] = v.u;
      }
    }
  }
  __syncthreads();

  f32x4 acc[2][8];
  const f32x4 zz = {0.f, 0.f, 0.f, 0.f};
  #pragma unroll
  for (int rt = 0; rt < 2; ++rt)
    #pragma unroll
    for (int ct = 0; ct < 8; ++ct) acc[rt][ct] = zz;

  const int wr = w*2;   // row-tile base (2 tiles of 16 rows per wave)

  // -------- layer 1: K=96 (3 k-tiles; tile 2 = noise rows) --------
  __builtin_amdgcn_s_setprio(1);
  #pragma unroll
  for (int kt = 0; kt < 3; ++kt){
    f16x8 B[8];
    #pragma unroll
    for (int ct = 0; ct < 8; ++ct) B[ct] = *(f16x8*)&Hb[((kt*8 + ct)*64 + lane)*8];
    #pragma unroll
    for (int rt = 0; rt < 2; ++rt){
      f16x8 A = *(const f16x8*)&w1f[(((wr + rt)*3 + kt)*64 + lane)*8];
      #pragma unroll
      for (int ct = 0; ct < 8; ++ct)
        acc[rt][ct] = MFMA_(A, B[ct], acc[rt][ct]);
    }
  }
  __builtin_amdgcn_s_setprio(0);
  __syncthreads();

  // -------- epilogue L1: bias+relu -> f16 fragment order (Bh1), pkrtz --------
  #pragma unroll
  for (int rt = 0; rt < 2; ++rt){
    const int row0 = w*32 + rt*16 + ((lane >> 4) << 2);
    const float4 bq = *(const float4*)&b1[row0];
    const int kt2 = row0 >> 5, c16 = (row0 >> 3) & 3, j0 = row0 & 7;
    const int lane2 = (lane & 15) + c16*16;
    #pragma unroll
    for (int ct = 0; ct < 8; ++ct){
      PK2 v;
      v.h[0] = __builtin_amdgcn_cvt_pkrtz(fmaxf(acc[rt][ct][0] + bq.x, 0.f),
                                          fmaxf(acc[rt][ct][1] + bq.y, 0.f));
      v.h[1] = __builtin_amdgcn_cvt_pkrtz(fmaxf(acc[rt][ct][2] + bq.z, 0.f),
                                          fmaxf(acc[rt][ct][3] + bq.w, 0.f));
      *(uint2*)&Hb[((kt2*8 + ct)*64 + lane2)*8 + j0] = v.u;
      acc[rt][ct] = zz;
    }
  }
  __syncthreads();

  // -------- layer 2: K=256 (8 k-tiles), simple loop (compiler schedules) --------
  __builtin_amdgcn_s_setprio(1);
  #pragma unroll 2
  for (int kt = 0; kt < 8; ++kt){
    f16x8 B[8];
    #pragma unroll
    for (int ct = 0; ct < 8; ++ct) B[ct] = *(f16x8*)&Hb[((kt*8 + ct)*64 + lane)*8];
    #pragma unroll
    for (int rt = 0; rt < 2; ++rt){
      f16x8 A = *(const f16x8*)&w2f[(((wr + rt)*8 + kt)*64 + lane)*8];
      #pragma unroll
      for (int ct = 0; ct < 8; ++ct)
        acc[rt][ct] = MFMA_(A, B[ct], acc[rt][ct]);
    }
  }
  __builtin_amdgcn_s_setprio(0);

  // ---- preload layer-3 A-frags (hide under epilogue L2) ----
  f16x8 W3v[8];
  #pragma unroll
  for (int kt = 0; kt < 8; ++kt) W3v[kt] = *(const f16x8*)&w3f[(kt*64 + lane)*8];
  __syncthreads();

  // -------- epilogue L2: bias+relu -> f16 fragment order (Bh2), pkrtz --------
  #pragma unroll
  for (int rt = 0; rt < 2; ++rt){
    const int row0 = w*32 + rt*16 + ((lane >> 4) << 2);
    const float4 bq = *(const float4*)&b2[row0];
    const int kt2 = row0 >> 5, c16 = (row0 >> 3) & 3, j0 = row0 & 7;
    const int lane2 = (lane & 15) + c16*16;
    #pragma unroll
    for (int ct = 0; ct < 8; ++ct){
      PK2 v;
      v.h[0] = __builtin_amdgcn_cvt_pkrtz(fmaxf(acc[rt][ct][0] + bq.x, 0.f),
                                          fmaxf(acc[rt][ct][1] + bq.y, 0.f));
      v.h[1] = __builtin_amdgcn_cvt_pkrtz(fmaxf(acc[rt][ct][2] + bq.z, 0.f),
                                          fmaxf(acc[rt][ct][3] + bq.w, 0.f));
      *(uint2*)&Hb[((kt2*8 + ct)*64 + lane2)*8 + j0] = v.u;
    }
  }
  __syncthreads();

  // -------- layer 3: rows 0..2, wave w handles col-tile w (8 waves <-> 8 cts) --------
  {
    f32x4 a3 = zz;
    __builtin_amdgcn_s_setprio(1);
    #pragma unroll
    for (int kt = 0; kt < 8; ++kt){
      f16x8 B = *(f16x8*)&Hb[((kt*8 + w)*64 + lane)*8];
      a3 = MFMA_(W3v[kt], B, a3);
    }
    __builtin_amdgcn_s_setprio(0);
    if (lane < 16){
      const float ox = a3[0] + b3[0];
      const float oy = a3[1] + b3[1];
      const float oz = a3[2] + b3[2];
      const float nrm = sqrtf(ox*ox + oy*oy + oz*oz);
      const float rg_ = fmaxf(nrm - (float)0.10825317547305482, 0.f);
      const int pt = w*16 + lane;
      const int cell = cells[pt];
      const float fx = ((float)(cell >> 8)        + 0.5f) * 0.0625f - 0.5f;
      const float fy = ((float)((cell >> 4) & 15) + 0.5f) * 0.0625f - 0.5f;
      const float fz = ((float)(cell & 15)        + 0.5f) * 0.0625f - 0.5f;
      const int pidx = p0 + pt;
      out[b*49152 +          pidx] = ox + fx;
      out[b*49152 + 16384 +  pidx] = oy + fy;
      out[b*49152 + 32768 +  pidx] = oz + fz;
      out[786432  + b*16384 + pidx] = rg_;
    }
  }
}

extern "C" void kernel_launch(void* const* d_in, const int* in_sizes, int n_in,
                              void* d_out, int out_size, void* d_ws, size_t ws_size,
                              hipStream_t stream){
  const float* x     = (const float*)d_in[0];
  const float* dens  = (const float*)d_in[1];
  const float* noise = (const float*)d_in[2];
  const float* W1    = (const float*)d_in[3];
  const float* b1    = (const float*)d_in[4];
  const float* W2    = (const float*)d_in[5];
  const float* b2    = (const float*)d_in[6];
  const float* W3    = (const float*)d_in[7];
  const float* b3    = (const float*)d_in[8];

  char* ws = (char*)d_ws;
  int*      pc   = (int*)(ws + 0);
  _Float16* w1f  = (_Float16*)(ws + OFF_W1F);
  _Float16* w2f  = (_Float16*)(ws + OFF_W2F);
  _Float16* w3f  = (_Float16*)(ws + OFF_W3F);
  _Float16* xT   = (_Float16*)(ws + OFF_XT);
  float*    out  = (float*)d_out;

  const bool use_xt = (ws_size >= (size_t)WS_NEED);
  const int  nprep  = use_xt ? 318 : 62;

  kP<<<dim3(nprep), dim3(256), 0, stream>>>(dens, pc, W1, W2, W3, x,
                                            w1f, w2f, w3f, xT);
  if (use_xt)
    kE<true ><<<dim3(128, 16), dim3(512), 0, stream>>>(x, xT, noise, w1f, w2f, w3f,
                                                       b1, b2, b3, pc, out);
  else
    kE<false><<<dim3(128, 16), dim3(512), 0, stream>>>(x, xT, noise, w1f, w2f, w3f,
                                                       b1, b2, b3, pc, out);
}

// Round 12
// 74.860 us; speedup vs baseline: 1.1302x; 1.0167x over previous
//
#include <hip/hip_runtime.h>

typedef unsigned long long u64;
typedef _Float16 f16x8 __attribute__((ext_vector_type(8)));
typedef float    f32x4 __attribute__((ext_vector_type(4)));
typedef __fp16   fp16x2 __attribute__((ext_vector_type(2)));

#define G_    4096
#define NPTS  16384

union H8 { _Float16 h[8]; uint4 u; };
union PK2 { fp16x2 h[2]; uint2 u; };
union PK4 { fp16x2 h[4]; uint4 u; };

#define MFMA_(A_,B_,C_) __builtin_amdgcn_mfma_f32_16x16x32_f16((A_),(B_),(C_),0,0,0)

// ---------------- ws layout (bytes) ----------------
// pc   i32 [16][16384]    @ 0        (1048576)
// w1f  f16 [16][3][64][8] @ 1048576  (49152)   A-frag order, 3 k-tiles (k=64..95 pad/noise)
// w2f  f16 [16][8][64][8] @ 1097728  (131072)
// w3f  f16 [8][64][8]     @ 1228800  (8192)    rows 3..15 zero
// xT   f16 [16][4096][64] @ 1236992  (8388608) transposed+f16 x (only if ws fits)
// total 9625600

#define OFF_W1F 1048576
#define OFF_W2F 1097728
#define OFF_W3F 1228800
#define OFF_XT  1236992
#define WS_NEED (OFF_XT + 8388608)

// ---- merged prep ----
// blocks 0..15   : sampling (one per batch)  [wave-scan rewrite, ~14 barriers vs ~57]
// blocks 16..61  : weight bake (11776 H8 entries)
// blocks 62..317 : x transpose -> f16 (only launched when use_xt)
__global__ __launch_bounds__(256) void kP(const float* __restrict__ dens,
                                          int* __restrict__ pc,
                                          const float* __restrict__ W1,
                                          const float* __restrict__ W2,
                                          const float* __restrict__ W3,
                                          const float* __restrict__ x,
                                          _Float16* __restrict__ w1f,
                                          _Float16* __restrict__ w2f,
                                          _Float16* __restrict__ w3f,
                                          _Float16* __restrict__ xT){
  __shared__ double sred[256];
  __shared__ u64  keys[4096];     // 32 KB
  __shared__ int  nvs[4096];      // 16 KB
  __shared__ int  binidx[4096];   // 16 KB
  __shared__ int  hist[1024];
  __shared__ int  wpA[4], wpB[4], wpC[4];
  __shared__ float Sf;
  __shared__ int  BstarS, needS, cntS;
  const int t = threadIdx.x;

  if (blockIdx.x >= 62){
    // ---------------- x transpose path: [64][4096] f32 -> [4096][64] f16 ----------------
    const int idx = blockIdx.x - 62;          // 0..255
    const int b = idx >> 4, blk = idx & 15;
    const int cell = blk*256 + t;
    const float* xb = x + ((size_t)b*64)*G_ + cell;
    _Float16* xo = xT + ((size_t)(b*G_ + cell))*64;
    #pragma unroll
    for (int c8 = 0; c8 < 8; ++c8){
      float a[8];
      #pragma unroll
      for (int j = 0; j < 8; ++j) a[j] = xb[(size_t)(c8*8 + j)*G_];
      PK4 v;
      v.h[0] = __builtin_amdgcn_cvt_pkrtz(a[0], a[1]);
      v.h[1] = __builtin_amdgcn_cvt_pkrtz(a[2], a[3]);
      v.h[2] = __builtin_amdgcn_cvt_pkrtz(a[4], a[5]);
      v.h[3] = __builtin_amdgcn_cvt_pkrtz(a[6], a[7]);
      *(uint4*)&xo[c8*8] = v.u;
    }
    return;
  }

  if (blockIdx.x >= 16){
    // ---------------- weight bake path ----------------
    const int e = (blockIdx.x - 16)*256 + t;   // 11776 entries
    H8 v;
    if (e < 8192){                                 // w2f: [RT 16][kt 8][lane 64]
      const int RT = e >> 9, kt = (e >> 6) & 7, l = e & 63;
      const int m = RT*16 + (l & 15), k = kt*32 + ((l >> 4) << 3);
      #pragma unroll
      for (int j = 0; j < 8; ++j) v.h[j] = (_Float16)W2[m*256 + k + j];
      *(uint4*)&w2f[e*8] = v.u;
    } else if (e < 11264){                         // w1f: [RT 16][kt 3][lane 64]
      const int e2 = e - 8192;
      const int RT = e2 / 192, r2 = e2 % 192, kt = r2 >> 6, l = r2 & 63;
      const int m = RT*16 + (l & 15), k = kt*32 + ((l >> 4) << 3);
      #pragma unroll
      for (int j = 0; j < 8; ++j) v.h[j] = (k + j < 66) ? (_Float16)W1[m*66 + k + j] : (_Float16)0.f;
      *(uint4*)&w1f[e2*8] = v.u;
    } else if (e < 11776){                         // w3f: [kt 8][lane 64]
      const int e3 = e - 11264;
      const int kt = e3 >> 6, l = e3 & 63;
      const int m = l & 15, k = kt*32 + ((l >> 4) << 3);
      #pragma unroll
      for (int j = 0; j < 8; ++j) v.h[j] = (m < 3) ? (_Float16)W3[m*256 + k + j] : (_Float16)0.f;
      *(uint4*)&w3f[e3*8] = v.u;
    }
    return;
  }

  // ---------------- sampling path (one block per batch) ----------------
  const int b = blockIdx.x;
  const float* d = dens + b*G_;
  const int lane = t & 63, wid = t >> 6;

  for (int j = t; j < 1024; j += 256) hist[j] = 0;
  if (t == 0){ cntS = 0; BstarS = 0x7fffffff; needS = 0; }

  // ---- S: EXACT same summation pattern as all passing rounds (do not touch) ----
  double s = 0.0;
  for (int j = 0; j < 16; ++j) s += (double)d[t + 256*j];
  sred[t] = s; __syncthreads();
  for (int off = 128; off > 0; off >>= 1){
    if (t < off) sred[t] += sred[t + off];
    __syncthreads();
  }
  if (t == 0) Sf = (float)sred[0];
  __syncthreads();
  const float S = Sf;

  // ---- keys, base counts, histogram ----
  int bi[16]; int bs = 0;
  #pragma unroll
  for (int j = 0; j < 16; ++j){
    const int i = t + 256*j;
    const float p  = d[i] / S;
    const float sc = p * 16384.0f;     // exact (x2^14)
    const float fl = floorf(sc);
    const float fr = sc - fl;          // exact
    bi[j] = (int)fl; bs += bi[j];
    const unsigned fb = __float_as_uint(fr);
    keys[i] = ((u64)fb << 12) | (u64)(4095 - i);
    atomicAdd(&hist[fb >> 20], 1);
  }
  // wave-reduce base sum -> 4 partials (integer, order-free)
  {
    int v = bs;
    v += __shfl_xor(v, 1);  v += __shfl_xor(v, 2);  v += __shfl_xor(v, 4);
    v += __shfl_xor(v, 8);  v += __shfl_xor(v, 16); v += __shfl_xor(v, 32);
    if (lane == 0) wpA[wid] = v;
  }
  __syncthreads();   // hist atomics + wpA visible
  const int rem = 16384 - (wpA[0] + wpA[1] + wpA[2] + wpA[3]);

  // ---- suffix counts from 1024-bin histogram (4 bins/thread) ----
  const int h0 = hist[4*t], h1 = hist[4*t+1], h2 = hist[4*t+2], h3 = hist[4*t+3];
  const int gs = h0 + h1 + h2 + h3;
  int incl = gs;    // inclusive prefix over 256 threads (wave scan + partials)
  {
    int n;
    n = __shfl_up(incl, 1);  if (lane >= 1)  incl += n;
    n = __shfl_up(incl, 2);  if (lane >= 2)  incl += n;
    n = __shfl_up(incl, 4);  if (lane >= 4)  incl += n;
    n = __shfl_up(incl, 8);  if (lane >= 8)  incl += n;
    n = __shfl_up(incl, 16); if (lane >= 16) incl += n;
    n = __shfl_up(incl, 32); if (lane >= 32) incl += n;
    if (lane == 63) wpB[wid] = incl;
  }
  __syncthreads();
  if (wid >= 1) incl += wpB[0];
  if (wid >= 2) incl += wpB[1];
  if (wid >= 3) incl += wpB[2];
  const int sAfter = 4096 - incl;     // total keys = 4096 (constant)
  const int ca3 = sAfter;
  const int ca2 = ca3 + h3;
  const int ca1 = ca2 + h2;
  const int ca0 = ca1 + h1;
  if (rem > 0){
    const int ca[4] = {ca0, ca1, ca2, ca3};
    const int hh[4] = {h0, h1, h2, h3};
    #pragma unroll
    for (int q = 0; q < 4; ++q)
      if (ca[q] < rem && rem <= ca[q] + hh[q]){ BstarS = 4*t + q; needS = rem - ca[q]; }
  }
  __syncthreads();
  const int Bstar = BstarS, need = needS;

  // ---- counts + exact ranking of the threshold bin ----
  #pragma unroll
  for (int j = 0; j < 16; ++j){
    const int i = t + 256*j;
    const int bin = (int)(keys[i] >> 32);
    nvs[i] = bi[j] + ((bin > Bstar) ? 1 : 0);
    if (bin == Bstar){ const int pos = atomicAdd(&cntS, 1); binidx[pos] = i; }
  }
  __syncthreads();
  const int cnt = cntS;
  for (int p = t; p < cnt; p += 256){
    const u64 K = keys[binidx[p]];
    int r = 0;
    for (int q = 0; q < cnt; ++q) r += (keys[binidx[q]] > K) ? 1 : 0;
    if (r < need) nvs[binidx[p]] += 1;
  }
  __syncthreads();

  // ---- prefix + expand (thread t owns cells t*16..t*16+15) ----
  int loc[16]; int ls = 0;
  #pragma unroll
  for (int j = 0; j < 16; ++j){ loc[j] = nvs[t*16 + j]; ls += loc[j]; }
  int incl2 = ls;
  {
    int n;
    n = __shfl_up(incl2, 1);  if (lane >= 1)  incl2 += n;
    n = __shfl_up(incl2, 2);  if (lane >= 2)  incl2 += n;
    n = __shfl_up(incl2, 4);  if (lane >= 4)  incl2 += n;
    n = __shfl_up(incl2, 8);  if (lane >= 8)  incl2 += n;
    n = __shfl_up(incl2, 16); if (lane >= 16) incl2 += n;
    n = __shfl_up(incl2, 32); if (lane >= 32) incl2 += n;
    if (lane == 63) wpC[wid] = incl2;
  }
  __syncthreads();
  if (wid >= 1) incl2 += wpC[0];
  if (wid >= 2) incl2 += wpC[1];
  if (wid >= 3) incl2 += wpC[2];
  int off0 = incl2 - ls;              // exclusive prefix
  int* o = pc + b*NPTS;
  #pragma unroll
  for (int j = 0; j < 16; ++j){
    const int c = t*16 + j;
    for (int r = 0; r < loc[j]; ++r) o[off0++] = c;
  }
}

// ---- fused MLP: 128 pts/block, 8 waves x 32 rows x 128 pts, acc = 64 regs ----
// regs ~110 < 128 => (512,4): 4 waves/SIMD, 2 blocks/CU (LDS 64.8KB), 16 waves/CU.
template<bool USE_XT>
__global__ __launch_bounds__(512, 4) void kE(
    const float* __restrict__ x, const _Float16* __restrict__ xT,
    const float* __restrict__ noise,
    const _Float16* __restrict__ w1f, const _Float16* __restrict__ w2f,
    const _Float16* __restrict__ w3f,
    const float* __restrict__ b1, const float* __restrict__ b2, const float* __restrict__ b3,
    const int* __restrict__ pc, float* __restrict__ out)
{
  __shared__ _Float16 Hb[32768];   // 64KB; reused: Bin(24KB) -> Bh1(64KB) -> Bh2(64KB)
  __shared__ int cells[128];
  const int b = blockIdx.y, p0 = blockIdx.x*128, tid = threadIdx.x;
  const int w = tid >> 6, lane = tid & 63;

  if (tid < 128) cells[tid] = pc[b*NPTS + p0 + tid];

  // ---- stage noise k-tile (kt=2): rows k=64,65 = noise, rest zero ----
  {
    const int ct = tid >> 6, l2 = tid & 63;            // ct 0..7
    const int k2 = l2 >> 4, pt = ct*16 + (l2 & 15);
    PK4 v; v.u = make_uint4(0u, 0u, 0u, 0u);
    if (k2 == 0){
      const float n0 = noise[(b*2 + 0)*NPTS + p0 + pt]*2.f - 1.f;
      const float n1 = noise[(b*2 + 1)*NPTS + p0 + pt]*2.f - 1.f;
      v.h[0] = __builtin_amdgcn_cvt_pkrtz(n0, n1);
    }
    *(uint4*)&Hb[((2*8 + ct)*64 + l2)*8] = v.u;
  }

  // ---- stage layer-1 x k-tiles (kt=0,1): 1024 tasks, 2 per thread ----
  // thread -> (pt = tid&127, koct = tid>>7 + 4i): lane-linear 16B-strided writes.
  {
    const int pt = tid & 127;
    const int cell = pc[b*NPTS + p0 + pt];
    const int ct = pt >> 4, sl = pt & 15;
    #pragma unroll
    for (int i = 0; i < 2; ++i){
      const int koct = (tid >> 7) + 4*i;
      const int kt = koct >> 2, k2 = koct & 3;
      const int lane2 = sl + k2*16;
      if (USE_XT){
        const uint4 v = *(const uint4*)&xT[((size_t)(b*G_ + cell))*64 + koct*8];
        *(uint4*)&Hb[((kt*8 + ct)*64 + lane2)*8] = v;
      } else {
        const float* xb = x + ((size_t)(b*64 + koct*8))*G_ + cell;
        float a[8];
        #pragma unroll
        for (int j = 0; j < 8; ++j) a[j] = xb[(size_t)j*G_];
        PK4 v;
        v.h[0] = __builtin_amdgcn_cvt_pkrtz(a[0], a[1]);
        v.h[1] = __builtin_amdgcn_cvt_pkrtz(a[2], a[3]);
        v.h[2] = __builtin_amdgcn_cvt_pkrtz(a[4], a[5]);
        v.h[3] = __builtin_amdgcn_cvt_pkrtz(a[6], a[7]);
        *(uint4*)&Hb[((kt*8 + ct)*64 + lane2)*8] = v.u;
      }
    }
  }
  __syncthreads();

  f32x4 acc[2][8];
  const f32x4 zz = {0.f, 0.f, 0.f, 0.f};
  #pragma unroll
  for (int rt = 0; rt < 2; ++rt)
    #pragma unroll
    for (int ct = 0; ct < 8; ++ct) acc[rt][ct] = zz;

  const int wr = w*2;   // row-tile base (2 tiles of 16 rows per wave)

  // -------- layer 1: K=96 (3 k-tiles; tile 2 = noise rows) --------
  __builtin_amdgcn_s_setprio(1);
  #pragma unroll
  for (int kt = 0; kt < 3; ++kt){
    f16x8 B[8];
    #pragma unroll
    for (int ct = 0; ct < 8; ++ct) B[ct] = *(f16x8*)&Hb[((kt*8 + ct)*64 + lane)*8];
    #pragma unroll
    for (int rt = 0; rt < 2; ++rt){
      f16x8 A = *(const f16x8*)&w1f[(((wr + rt)*3 + kt)*64 + lane)*8];
      #pragma unroll
      for (int ct = 0; ct < 8; ++ct)
        acc[rt][ct] = MFMA_(A, B[ct], acc[rt][ct]);
    }
  }
  __builtin_amdgcn_s_setprio(0);
  __syncthreads();

  // -------- epilogue L1: bias+relu -> f16 fragment order (Bh1), pkrtz --------
  #pragma unroll
  for (int rt = 0; rt < 2; ++rt){
    const int row0 = w*32 + rt*16 + ((lane >> 4) << 2);
    const float4 bq = *(const float4*)&b1[row0];
    const int kt2 = row0 >> 5, c16 = (row0 >> 3) & 3, j0 = row0 & 7;
    const int lane2 = (lane & 15) + c16*16;
    #pragma unroll
    for (int ct = 0; ct < 8; ++ct){
      PK2 v;
      v.h[0] = __builtin_amdgcn_cvt_pkrtz(fmaxf(acc[rt][ct][0] + bq.x, 0.f),
                                          fmaxf(acc[rt][ct][1] + bq.y, 0.f));
      v.h[1] = __builtin_amdgcn_cvt_pkrtz(fmaxf(acc[rt][ct][2] + bq.z, 0.f),
                                          fmaxf(acc[rt][ct][3] + bq.w, 0.f));
      *(uint2*)&Hb[((kt2*8 + ct)*64 + lane2)*8 + j0] = v.u;
      acc[rt][ct] = zz;
    }
  }
  __syncthreads();

  // -------- layer 2: K=256 (8 k-tiles), simple loop (compiler schedules) --------
  __builtin_amdgcn_s_setprio(1);
  #pragma unroll 2
  for (int kt = 0; kt < 8; ++kt){
    f16x8 B[8];
    #pragma unroll
    for (int ct = 0; ct < 8; ++ct) B[ct] = *(f16x8*)&Hb[((kt*8 + ct)*64 + lane)*8];
    #pragma unroll
    for (int rt = 0; rt < 2; ++rt){
      f16x8 A = *(const f16x8*)&w2f[(((wr + rt)*8 + kt)*64 + lane)*8];
      #pragma unroll
      for (int ct = 0; ct < 8; ++ct)
        acc[rt][ct] = MFMA_(A, B[ct], acc[rt][ct]);
    }
  }
  __builtin_amdgcn_s_setprio(0);

  // ---- preload layer-3 A-frags (hide under epilogue L2) ----
  f16x8 W3v[8];
  #pragma unroll
  for (int kt = 0; kt < 8; ++kt) W3v[kt] = *(const f16x8*)&w3f[(kt*64 + lane)*8];
  __syncthreads();

  // -------- epilogue L2: bias+relu -> f16 fragment order (Bh2), pkrtz --------
  #pragma unroll
  for (int rt = 0; rt < 2; ++rt){
    const int row0 = w*32 + rt*16 + ((lane >> 4) << 2);
    const float4 bq = *(const float4*)&b2[row0];
    const int kt2 = row0 >> 5, c16 = (row0 >> 3) & 3, j0 = row0 & 7;
    const int lane2 = (lane & 15) + c16*16;
    #pragma unroll
    for (int ct = 0; ct < 8; ++ct){
      PK2 v;
      v.h[0] = __builtin_amdgcn_cvt_pkrtz(fmaxf(acc[rt][ct][0] + bq.x, 0.f),
                                          fmaxf(acc[rt][ct][1] + bq.y, 0.f));
      v.h[1] = __builtin_amdgcn_cvt_pkrtz(fmaxf(acc[rt][ct][2] + bq.z, 0.f),
                                          fmaxf(acc[rt][ct][3] + bq.w, 0.f));
      *(uint2*)&Hb[((kt2*8 + ct)*64 + lane2)*8 + j0] = v.u;
    }
  }
  __syncthreads();

  // -------- layer 3: rows 0..2, wave w handles col-tile w (8 waves <-> 8 cts) --------
  {
    f32x4 a3 = zz;
    __builtin_amdgcn_s_setprio(1);
    #pragma unroll
    for (int kt = 0; kt < 8; ++kt){
      f16x8 B = *(f16x8*)&Hb[((kt*8 + w)*64 + lane)*8];
      a3 = MFMA_(W3v[kt], B, a3);
    }
    __builtin_amdgcn_s_setprio(0);
    if (lane < 16){
      const float ox = a3[0] + b3[0];
      const float oy = a3[1] + b3[1];
      const float oz = a3[2] + b3[2];
      const float nrm = sqrtf(ox*ox + oy*oy + oz*oz);
      const float rg_ = fmaxf(nrm - (float)0.10825317547305482, 0.f);
      const int pt = w*16 + lane;
      const int cell = cells[pt];
      const float fx = ((float)(cell >> 8)        + 0.5f) * 0.0625f - 0.5f;
      const float fy = ((float)((cell >> 4) & 15) + 0.5f) * 0.0625f - 0.5f;
      const float fz = ((float)(cell & 15)        + 0.5f) * 0.0625f - 0.5f;
      const int pidx = p0 + pt;
      out[b*49152 +          pidx] = ox + fx;
      out[b*49152 + 16384 +  pidx] = oy + fy;
      out[b*49152 + 32768 +  pidx] = oz + fz;
      out[786432  + b*16384 + pidx] = rg_;
    }
  }
}

extern "C" void kernel_launch(void* const* d_in, const int* in_sizes, int n_in,
                              void* d_out, int out_size, void* d_ws, size_t ws_size,
                              hipStream_t stream){
  const float* x     = (const float*)d_in[0];
  const float* dens  = (const float*)d_in[1];
  const float* noise = (const float*)d_in[2];
  const float* W1    = (const float*)d_in[3];
  const float* b1    = (const float*)d_in[4];
  const float* W2    = (const float*)d_in[5];
  const float* b2    = (const float*)d_in[6];
  const float* W3    = (const float*)d_in[7];
  const float* b3    = (const float*)d_in[8];

  char* ws = (char*)d_ws;
  int*      pc   = (int*)(ws + 0);
  _Float16* w1f  = (_Float16*)(ws + OFF_W1F);
  _Float16* w2f  = (_Float16*)(ws + OFF_W2F);
  _Float16* w3f  = (_Float16*)(ws + OFF_W3F);
  _Float16* xT   = (_Float16*)(ws + OFF_XT);
  float*    out  = (float*)d_out;

  const bool use_xt = (ws_size >= (size_t)WS_NEED);
  const int  nprep  = use_xt ? 318 : 62;

  kP<<<dim3(nprep), dim3(256), 0, stream>>>(dens, pc, W1, W2, W3, x,
                                            w1f, w2f, w3f, xT);
  if (use_xt)
    kE<true ><<<dim3(128, 16), dim3(512), 0, stream>>>(x, xT, noise, w1f, w2f, w3f,
                                                       b1, b2, b3, pc, out);
  else
    kE<false><<<dim3(128, 16), dim3(512), 0, stream>>>(x, xT, noise, w1f, w2f, w3f,
                                                       b1, b2, b3, pc, out);
}